// Round 2
// baseline (348.165 us; speedup 1.0000x reference)
//
#include <hip/hip_runtime.h>

#define TINY 1e-6f

constexpr int S_SAMPLES = 64;
constexpr int N_PIX = 256 * 512;

__device__ __forceinline__ float clamp01(float x) {
    return fminf(fmaxf(x, 0.0f), 1.0f);
}

__global__ void __launch_bounds__(256)
shade_kernel(const float* __restrict__ normal,     // N*3
             const float* __restrict__ albedo,     // N*3
             const float* __restrict__ roughness,  // N*1
             const float* __restrict__ points,     // N*3
             const float* __restrict__ cam,        // 3
             const float* __restrict__ ldir,       // N*S*3
             const float* __restrict__ dlight,     // N*S*3
             const float* __restrict__ hdir,       // N*S*3
             const float* __restrict__ slight,     // N*S*3
             float* __restrict__ out)              // N*3
{
    const int wave = threadIdx.x >> 6;   // 4 waves per block
    const int lane = threadIdx.x & 63;   // = sample index (S == 64)
    const int pix  = blockIdx.x * 4 + wave;

    // ---- per-pixel scalars (wave-uniform broadcast loads) ----
    const float nx = normal[pix * 3 + 0];
    const float ny = normal[pix * 3 + 1];
    const float nz = normal[pix * 3 + 2];
    const float r  = roughness[pix];
    const float px = points[pix * 3 + 0];
    const float py = points[pix * 3 + 1];
    const float pz = points[pix * 3 + 2];
    const float cx = cam[0], cy = cam[1], cz = cam[2];

    // view = normalize(cam - p)
    const float dx = cx - px, dy = cy - py, dz = cz - pz;
    const float len = sqrtf(dx * dx + dy * dy + dz * dz);
    const float inv = 1.0f / fmaxf(len, 1e-4f);
    const float vx = dx * inv, vy = dy * inv, vz = dz * inv;

    const float ndv = clamp01(nx * vx + ny * vy + nz * vz);
    const float k   = (r + 1.0f) * (r + 1.0f) * 0.125f;
    const float omk = 1.0f - k;
    const float g1v = ndv / fmaxf(ndv * omk + k, TINY);

    // ---- per-lane: one sample = 3 consecutive floats per array ----
    const long base = ((long)pix * S_SAMPLES + lane) * 3;

    const float lx = ldir[base + 0], ly = ldir[base + 1], lz = ldir[base + 2];
    const float d0 = dlight[base + 0], d1 = dlight[base + 1], d2 = dlight[base + 2];
    const float hx = hdir[base + 0], hy = hdir[base + 1], hz = hdir[base + 2];
    const float s0 = slight[base + 0], s1 = slight[base + 1], s2 = slight[base + 2];

    // diffuse: dlight * ndl_d  (albedo * 2 / S folded in after reduction)
    const float ndl_d = clamp01(nx * lx + ny * ly + nz * lz);
    float dacc0 = d0 * ndl_d;
    float dacc1 = d1 * ndl_d;
    float dacc2 = d2 * ndl_d;

    // specular
    const float vdh = clamp01(hx * vx + hy * vy + hz * vz);
    const float tv  = 2.0f * vdh;
    const float lsx = tv * hx - vx;
    const float lsy = tv * hy - vy;
    const float lsz = tv * hz - vz;
    const float ndl = clamp01(nx * lsx + ny * lsy + nz * lsz);
    const float ndh = clamp01(nx * hx + ny * hy + nz * hz);
    const float f   = 0.04f + 0.96f * exp2f((-5.55472f * vdh - 6.98316f) * vdh);
    const float g1l = ndl / fmaxf(ndl * omk + k, TINY);
    const float brdf = f * (g1l * g1v) / fmaxf(4.0f * ndl * ndv, TINY);
    const float w    = brdf * ndl * 4.0f * vdh / fmaxf(ndh, TINY);
    float sacc0 = s0 * w;
    float sacc1 = s1 * w;
    float sacc2 = s2 * w;

    // ---- butterfly reduction across the full 64-lane wave ----
#pragma unroll
    for (int off = 1; off < 64; off <<= 1) {
        dacc0 += __shfl_xor(dacc0, off);
        dacc1 += __shfl_xor(dacc1, off);
        dacc2 += __shfl_xor(dacc2, off);
        sacc0 += __shfl_xor(sacc0, off);
        sacc1 += __shfl_xor(sacc1, off);
        sacc2 += __shfl_xor(sacc2, off);
    }

    if (lane == 0) {
        const float ax = albedo[pix * 3 + 0];
        const float ay = albedo[pix * 3 + 1];
        const float az = albedo[pix * 3 + 2];
        const float inv_s = 1.0f / (float)S_SAMPLES;
        out[pix * 3 + 0] = (dacc0 * ax * 2.0f + sacc0) * inv_s;
        out[pix * 3 + 1] = (dacc1 * ay * 2.0f + sacc1) * inv_s;
        out[pix * 3 + 2] = (dacc2 * az * 2.0f + sacc2) * inv_s;
    }
}

extern "C" void kernel_launch(void* const* d_in, const int* in_sizes, int n_in,
                              void* d_out, int out_size, void* d_ws, size_t ws_size,
                              hipStream_t stream) {
    const float* normal    = (const float*)d_in[0];
    const float* albedo    = (const float*)d_in[1];
    const float* roughness = (const float*)d_in[2];
    const float* points    = (const float*)d_in[3];
    const float* cam       = (const float*)d_in[4];
    const float* ldir      = (const float*)d_in[5];
    const float* dlight    = (const float*)d_in[6];
    const float* hdir      = (const float*)d_in[7];
    const float* slight    = (const float*)d_in[8];
    float* out = (float*)d_out;

    // 4 pixels per 256-thread block (1 wave per pixel, 1 sample per lane)
    const int blocks = N_PIX / 4;  // 32768
    shade_kernel<<<blocks, 256, 0, stream>>>(normal, albedo, roughness, points,
                                             cam, ldir, dlight, hdir, slight, out);
}

// Round 3
// 344.945 us; speedup vs baseline: 1.0093x; 1.0093x over previous
//
#include <hip/hip_runtime.h>

#define TINY 1e-6f

constexpr int N_PIX = 256 * 512;   // 131072 pixels, S = 64 samples each

__device__ __forceinline__ float clamp01(float x) {
    return fminf(fmaxf(x, 0.0f), 1.0f);
}

// fast reciprocal: v_rcp_f32 (~1 ulp) — tolerance is 9.3e-3 absolute, plenty
__device__ __forceinline__ float frcp(float x) {
    return __builtin_amdgcn_rcpf(x);
}

// component i (0..11) of three packed float4s; i is a constant after unroll
__device__ __forceinline__ float cget(const float4& a, const float4& b, const float4& c, int i) {
    switch (i) {
        case 0:  return a.x; case 1:  return a.y; case 2:  return a.z; case 3:  return a.w;
        case 4:  return b.x; case 5:  return b.y; case 6:  return b.z; case 7:  return b.w;
        case 8:  return c.x; case 9:  return c.y; case 10: return c.z; default: return c.w;
    }
}

__global__ void __launch_bounds__(256)
shade_kernel(const float* __restrict__ normal,     // N*3
             const float* __restrict__ albedo,     // N*3
             const float* __restrict__ roughness,  // N*1
             const float* __restrict__ points,     // N*3
             const float* __restrict__ cam,        // 3
             const float* __restrict__ ldir,       // N*S*3
             const float* __restrict__ dlight,     // N*S*3
             const float* __restrict__ hdir,       // N*S*3
             const float* __restrict__ slight,     // N*S*3
             float* __restrict__ out)              // N*3
{
    const int t   = threadIdx.x;
    const int grp = t >> 4;          // 16 pixel-groups per 256-thread block
    const int sub = t & 15;          // lane within group: handles samples 4*sub..4*sub+3
    const int pix = blockIdx.x * 16 + grp;

    // ---- big-array loads first: 12 x global_load_dwordx4 in flight ----
    // lane's 4 samples are 12 consecutive floats (48 B, 16B-aligned)
    const size_t fbase = (size_t)pix * 192 + (size_t)sub * 12;
    const float4* Lp = (const float4*)(ldir   + fbase);
    const float4* Dp = (const float4*)(dlight + fbase);
    const float4* Hp = (const float4*)(hdir   + fbase);
    const float4* Sp = (const float4*)(slight + fbase);
    const float4 L0 = Lp[0], L1 = Lp[1], L2 = Lp[2];
    const float4 D0 = Dp[0], D1 = Dp[1], D2 = Dp[2];
    const float4 H0 = Hp[0], H1 = Hp[1], H2 = Hp[2];
    const float4 S0 = Sp[0], S1 = Sp[1], S2 = Sp[2];

    // ---- per-pixel scalars ----
    const float nx = normal[pix * 3 + 0];
    const float ny = normal[pix * 3 + 1];
    const float nz = normal[pix * 3 + 2];
    const float r  = roughness[pix];
    const float px = points[pix * 3 + 0];
    const float py = points[pix * 3 + 1];
    const float pz = points[pix * 3 + 2];
    const float cx = cam[0], cy = cam[1], cz = cam[2];

    // view = normalize(cam - p)
    const float dx = cx - px, dy = cy - py, dz = cz - pz;
    const float len = sqrtf(dx * dx + dy * dy + dz * dz);
    const float inv = frcp(fmaxf(len, 1e-4f));
    const float vx = dx * inv, vy = dy * inv, vz = dz * inv;

    const float ndv = clamp01(nx * vx + ny * vy + nz * vz);
    const float k   = (r + 1.0f) * (r + 1.0f) * 0.125f;
    const float omk = 1.0f - k;
    const float g1v = ndv * frcp(fmaxf(ndv * omk + k, TINY));

    float dacc0 = 0.f, dacc1 = 0.f, dacc2 = 0.f;
    float sacc0 = 0.f, sacc1 = 0.f, sacc2 = 0.f;

#pragma unroll
    for (int j = 0; j < 4; ++j) {
        const int e = j * 3;
        const float lx = cget(L0, L1, L2, e + 0);
        const float ly = cget(L0, L1, L2, e + 1);
        const float lz = cget(L0, L1, L2, e + 2);
        const float d0 = cget(D0, D1, D2, e + 0);
        const float d1 = cget(D0, D1, D2, e + 1);
        const float d2 = cget(D0, D1, D2, e + 2);
        const float hx = cget(H0, H1, H2, e + 0);
        const float hy = cget(H0, H1, H2, e + 1);
        const float hz = cget(H0, H1, H2, e + 2);
        const float s0 = cget(S0, S1, S2, e + 0);
        const float s1 = cget(S0, S1, S2, e + 1);
        const float s2 = cget(S0, S1, S2, e + 2);

        // diffuse: dlight * ndl_d   (albedo * 2 / S folded in after reduction)
        const float ndl_d = clamp01(nx * lx + ny * ly + nz * lz);
        dacc0 += d0 * ndl_d;
        dacc1 += d1 * ndl_d;
        dacc2 += d2 * ndl_d;

        // specular
        const float vdh = clamp01(hx * vx + hy * vy + hz * vz);
        const float tv  = 2.0f * vdh;
        const float lsx = tv * hx - vx;
        const float lsy = tv * hy - vy;
        const float lsz = tv * hz - vz;
        const float ndl = clamp01(nx * lsx + ny * lsy + nz * lsz);
        const float ndh = clamp01(nx * hx + ny * hy + nz * hz);
        const float f   = 0.04f + 0.96f * exp2f((-5.55472f * vdh - 6.98316f) * vdh);
        const float g1l = ndl * frcp(fmaxf(ndl * omk + k, TINY));
        const float brdf = f * g1l * g1v * frcp(fmaxf(4.0f * ndl * ndv, TINY));
        const float w    = brdf * ndl * 4.0f * vdh * frcp(fmaxf(ndh, TINY));
        sacc0 += s0 * w;
        sacc1 += s1 * w;
        sacc2 += s2 * w;
    }

    // ---- butterfly reduction within each 16-lane group (xor < 16 stays in-group) ----
#pragma unroll
    for (int off = 1; off < 16; off <<= 1) {
        dacc0 += __shfl_xor(dacc0, off);
        dacc1 += __shfl_xor(dacc1, off);
        dacc2 += __shfl_xor(dacc2, off);
        sacc0 += __shfl_xor(sacc0, off);
        sacc1 += __shfl_xor(sacc1, off);
        sacc2 += __shfl_xor(sacc2, off);
    }

    if (sub == 0) {
        const float ax = albedo[pix * 3 + 0];
        const float ay = albedo[pix * 3 + 1];
        const float az = albedo[pix * 3 + 2];
        const float inv_s = 1.0f / 64.0f;
        out[pix * 3 + 0] = (dacc0 * ax * 2.0f + sacc0) * inv_s;
        out[pix * 3 + 1] = (dacc1 * ay * 2.0f + sacc1) * inv_s;
        out[pix * 3 + 2] = (dacc2 * az * 2.0f + sacc2) * inv_s;
    }
}

extern "C" void kernel_launch(void* const* d_in, const int* in_sizes, int n_in,
                              void* d_out, int out_size, void* d_ws, size_t ws_size,
                              hipStream_t stream) {
    const float* normal    = (const float*)d_in[0];
    const float* albedo    = (const float*)d_in[1];
    const float* roughness = (const float*)d_in[2];
    const float* points    = (const float*)d_in[3];
    const float* cam       = (const float*)d_in[4];
    const float* ldir      = (const float*)d_in[5];
    const float* dlight    = (const float*)d_in[6];
    const float* hdir      = (const float*)d_in[7];
    const float* slight    = (const float*)d_in[8];
    float* out = (float*)d_out;

    // 16 pixels per 256-thread block (16 lanes/pixel, 4 samples/lane)
    const int blocks = N_PIX / 16;  // 8192
    shade_kernel<<<blocks, 256, 0, stream>>>(normal, albedo, roughness, points,
                                             cam, ldir, dlight, hdir, slight, out);
}